// Round 21
// baseline (128.532 us; speedup 1.0000x reference)
//
#include <hip/hip_runtime.h>
#include <math.h>

// Fused Actor network via single-term fp16 MFMA. Round 21: r20 + waves_per_eu(6,6).
// r20 proved: (a) asm-MFMA hazard handling correct (PASS, absmax 1.95e-3);
// (b) "+v" VGPR-pinned accs DO unlock 6 waves/SIMD (occupancy 57%);
// (c) waves_per_eu(6) is a MINIMUM -> allocator over-squeezed to 40 regs and spilled
//     (WRITE 168MB). Demand ~75 <= budget 85 (=512/6) -> pin BOTH bounds: (6,6).
// Single change vs r20. Block = 32 samples, 512 threads = 8 waves, LDS 41,216 B
// -> 3 blocks/CU. Bias-fold, f32 coeffs in CF, fast tanh, depth-2 prefetch.
// Weights pre-tiled in d_ws (per-wave 1KB bursts). LDS XOR-swizzle byte^=(row&7)<<4.

typedef __attribute__((ext_vector_type(8))) _Float16 half8;
typedef __attribute__((ext_vector_type(4))) _Float16 half4;
typedef __attribute__((ext_vector_type(4))) float    f32x4;

__device__ __forceinline__ f32x4 mfma16(half8 a, half8 b, f32x4 c) {
    // s_nop 1: 2 wait states for any VALU write (acc init / copies) -> MFMA read.
    // "v" = VGPR class -> no 64-AGPR allocation granule.
    asm("s_nop 1\n\tv_mfma_f32_16x16x32_f16 %0, %1, %2, %0" : "+v"(c) : "v"(a), "v"(b));
    return c;
}
#define MFMA16(a, b, c) mfma16((a), (b), (c))
// fence between MFMA chain and VALU reads of results (rule #18: need sched_barrier to
// pin ordering; s_nops cover MFMA-write -> VALU-read wait states).
#define MFMA_FENCE() do {                                    \
    __builtin_amdgcn_sched_barrier(0);                       \
    asm volatile("s_nop 7\n\ts_nop 7" ::: );                 \
    __builtin_amdgcn_sched_barrier(0);                       \
} while (0)

#define SWZ(row) (((row) & 7) << 4)

#define MT 32
#define T  512

// ---- LDS byte offsets (total 41,216 B) ----
// S  [0, 24576): 32 rows x 384 f16 (stride 768B); col376 = 1.0 (bias), 377..383 = 0.
// G1 [24576, 32768): 32x128 f16 (stride 256B)
// G2 [32768, 40960): 32x128 f16
// H1 [24576, 40960): 32x256 f16 (stride 512B), overlays G1+G2 (dead after A3)
// H2 [24576, 32768): 32x128 f16, overlays H1 low half (barrier inside E2)
// CF [40960, 41216): 32 x (c0,c1) f32
#define S_B      0
#define G1_B     24576
#define G2_B     32768
#define H1_B     24576
#define H2_B     24576
#define CF_B     40960
#define LDS_BYTES 41216

// ---- ws half-element offsets; tiled: tile(n0,kc) at ((n0*KC+kc)*512), [lane][8] ----
#define WS_W1 0        /* bw1: N0=8,  KC=12 (k=376 holds bb1) */
#define WS_W2 49152    /* bw2: N0=8,  KC=4 */
#define WS_E1 65536    /* ew1: N0=32, KC=12 (k=376 holds eb1) */
#define WS_E2 262144   /* ew2: N0=16, KC=8 */
#define WS_EM 327680   /* ewm: N0=4,  KC=4 (2 experts x 32 rows padded) */
#define WS_HALFS 335872
#define WS_BYTES 671744

__device__ __forceinline__ half8 cvt8(const float* __restrict__ p) {
    const float4 a = *reinterpret_cast<const float4*>(p);
    const float4 b = *reinterpret_cast<const float4*>(p + 4);
    half8 r;
    r[0] = (_Float16)a.x; r[1] = (_Float16)a.y; r[2] = (_Float16)a.z; r[3] = (_Float16)a.w;
    r[4] = (_Float16)b.x; r[5] = (_Float16)b.y; r[6] = (_Float16)b.z; r[7] = (_Float16)b.w;
    return r;
}

// ================= prep kernel: fp32 weights -> fp16 B-fragment tiles in ws =================
__global__ __launch_bounds__(256)
void prep_weights(const float* __restrict__ bw1, const float* __restrict__ bb1,
                  const float* __restrict__ bw2,
                  const float* __restrict__ ew1, const float* __restrict__ eb1,
                  const float* __restrict__ ew2,
                  const float* __restrict__ ewm, _Float16* __restrict__ wsw)
{
    const int i = blockIdx.x * 256 + threadIdx.x;
    if (i >= WS_HALFS) return;
    int sec; const float* W; const float* Bv; int N, K, KC, j0;
    if      (i < 49152)  { sec = 0; W = bw1; Bv = bb1;     N = 128; K = 376; KC = 12; j0 = i - WS_W1; }
    else if (i < 65536)  { sec = 1; W = bw2; Bv = nullptr; N = 128; K = 128; KC = 4;  j0 = i - WS_W2; }
    else if (i < 262144) { sec = 2; W = ew1; Bv = eb1;     N = 512; K = 376; KC = 12; j0 = i - WS_E1; }
    else if (i < 327680) { sec = 3; W = ew2; Bv = nullptr; N = 256; K = 256; KC = 8;  j0 = i - WS_E2; }
    else                 { sec = 4; W = ewm; Bv = nullptr; N = 34;  K = 128; KC = 4;  j0 = i - WS_EM; }
    const int tile = j0 >> 9;
    const int rem  = j0 & 511;
    const int l    = rem >> 3;
    const int jj   = rem & 7;
    const int n0   = tile / KC, kc = tile - n0 * KC;
    const int n = n0 * 16 + (l & 15);
    const int k = kc * 32 + (l >> 4) * 8 + jj;
    float v = 0.f;
    if (sec == 4) {
        const int e = n >> 5, a = n & 31;
        if (a < 17 && k < K) v = ewm[(e * 17 + a) * K + k];
    } else if (n < N) {
        if (k < K)             v = W[n * K + k];
        else if (k == K && Bv) v = Bv[n];
    }
    wsw[i] = (_Float16)v;
}

// ================= fused actor kernel =================
template <bool USE_WS>
__global__ __launch_bounds__(512)
__attribute__((amdgpu_waves_per_eu(6, 6)))
void actor_kernel(const float* __restrict__ states,
                  const float* __restrict__ bw1, const float* __restrict__ bb1,
                  const float* __restrict__ bw2, const float* __restrict__ bb2,
                  const float* __restrict__ bwo, const float* __restrict__ bbo,
                  const float* __restrict__ ew1, const float* __restrict__ eb1,
                  const float* __restrict__ ew2, const float* __restrict__ eb2,
                  const float* __restrict__ ewm, const float* __restrict__ ebm,
                  const _Float16* __restrict__ wsw,
                  float* __restrict__ out)
{
    extern __shared__ char smc[];
    const int t    = threadIdx.x;
    const int l    = t & 63;
    const int l15  = l & 15;
    const int kgrp = l >> 4;
    const int kg16 = kgrp * 16;
    const int wv   = __builtin_amdgcn_readfirstlane(t >> 6);
    const int base = blockIdx.x * MT;
    const int lB   = l * 8;

    const half8 zf = {0,0,0,0,0,0,0,0};

    // ---------- stage ----------
    {
        const float4* src = reinterpret_cast<const float4*>(states + (long)base * 376);
        for (int q = t; q < MT * 94; q += T) {
            const int r  = q / 94;
            const int c4 = q - r * 94;
            const float4 v = src[q];
            half4 h;
            h[0] = (_Float16)v.x; h[1] = (_Float16)v.y;
            h[2] = (_Float16)v.z; h[3] = (_Float16)v.w;
            *(half4*)(smc + S_B + ((r * 768 + c4 * 8) ^ SWZ(r))) = h;
        }
        if (t < MT) {
            const int off = (t * 768 + 752) ^ SWZ(t);
            *(ushort4*)(smc + S_B + off)     = make_ushort4(0x3C00u, 0, 0, 0);
            *(ushort4*)(smc + S_B + off + 8) = make_ushort4(0, 0, 0, 0);
        }
    }
    __syncthreads();

    // ---------- A1: G1 = relu(S @ bw1^T [+bb1 via pad])  M=32 N=128 K=384 ----------
    {
        f32x4 acc[2] = {{0,0,0,0},{0,0,0,0}};
        const int col = wv * 16 + l15;
        auto ldW = [&](int kc) -> half8 {
            if constexpr (USE_WS) return *(const half8*)(wsw + WS_W1 + (wv * 12 + kc) * 512 + lB);
            else {
                const int g = kc * 4 + kgrp;
                if (g < 47) return cvt8(bw1 + col * 376 + g * 8);
                half8 rr = zf; rr[0] = (_Float16)bb1[col]; return rr;
            }
        };
        half8 bq[2] = { ldW(0), ldW(1) };
        #pragma unroll
        for (int kc = 0; kc < 12; ++kc) {
            const half8 cur = bq[kc & 1];
            if (kc + 2 < 12) bq[kc & 1] = ldW(kc + 2);
            const int koff = kc * 64 + kg16;
            #pragma unroll
            for (int mt = 0; mt < 2; ++mt) {
                const int row = mt * 16 + l15;
                const half8 af = *(const half8*)(smc + S_B + ((row * 768 + koff) ^ SWZ(row)));
                acc[mt] = MFMA16(af, cur, acc[mt]);
            }
        }
        MFMA_FENCE();
        #pragma unroll
        for (int mt = 0; mt < 2; ++mt) {
            #pragma unroll
            for (int j = 0; j < 4; ++j) {
                const int row = mt * 16 + kgrp * 4 + j;
                const float v = fmaxf(acc[mt][j], 0.f);   // bias in acc
                *(_Float16*)(smc + G1_B + ((row * 256 + col * 2) ^ SWZ(row))) = (_Float16)v;
            }
        }
    }
    __syncthreads();

    // ---------- A2: G2 = relu(G1 @ bw2^T + bb2)  M=32 N=128 K=128 ----------
    {
        f32x4 acc[2] = {{0,0,0,0},{0,0,0,0}};
        const int col = wv * 16 + l15;
        auto ldW = [&](int kc) -> half8 {
            if constexpr (USE_WS) return *(const half8*)(wsw + WS_W2 + (wv * 4 + kc) * 512 + lB);
            else                  return cvt8(bw2 + col * 128 + (kc * 4 + kgrp) * 8);
        };
        half8 bq[2] = { ldW(0), ldW(1) };
        #pragma unroll
        for (int kc = 0; kc < 4; ++kc) {
            const half8 cur = bq[kc & 1];
            if (kc + 2 < 4) bq[kc & 1] = ldW(kc + 2);
            const int koff = kc * 64 + kg16;
            #pragma unroll
            for (int mt = 0; mt < 2; ++mt) {
                const int row = mt * 16 + l15;
                const half8 af = *(const half8*)(smc + G1_B + ((row * 256 + koff) ^ SWZ(row)));
                acc[mt] = MFMA16(af, cur, acc[mt]);
            }
        }
        MFMA_FENCE();
        const float bias = bb2[col];
        #pragma unroll
        for (int mt = 0; mt < 2; ++mt) {
            #pragma unroll
            for (int j = 0; j < 4; ++j) {
                const int row = mt * 16 + kgrp * 4 + j;
                const float v = fmaxf(acc[mt][j] + bias, 0.f);
                *(_Float16*)(smc + G2_B + ((row * 256 + col * 2) ^ SWZ(row))) = (_Float16)v;
            }
        }
    }
    __syncthreads();

    // ---------- A3: softmax coeffs -> f32 (c0,c1) in CF ----------
    {
        const int s     = t >> 4;
        const int r     = t & 15;
        const int e     = r & 1;
        const int chunk = r >> 1;
        float z = 0.f;
        const float* wo = bwo + e * 128 + chunk * 16;
        #pragma unroll
        for (int q = 0; q < 2; ++q) {
            const half8 hv = *(const half8*)(smc + G2_B + ((s * 256 + chunk * 32 + q * 16) ^ SWZ(s)));
            const float4 w0 = *(const float4*)(wo + q * 8);
            const float4 w1 = *(const float4*)(wo + q * 8 + 4);
            z = fmaf((float)hv[0], w0.x, z); z = fmaf((float)hv[1], w0.y, z);
            z = fmaf((float)hv[2], w0.z, z); z = fmaf((float)hv[3], w0.w, z);
            z = fmaf((float)hv[4], w1.x, z); z = fmaf((float)hv[5], w1.y, z);
            z = fmaf((float)hv[6], w1.z, z); z = fmaf((float)hv[7], w1.w, z);
        }
        z += __shfl_xor(z, 2, 64);
        z += __shfl_xor(z, 4, 64);
        z += __shfl_xor(z, 8, 64);
        z += bbo[e];
        const float zo = __shfl_xor(z, 1, 64);
        if (r < 2) {
            const float m = fmaxf(z, zo);
            const float ea = __expf(z - m), eb = __expf(zo - m);
            *(float*)(smc + CF_B + s * 8 + e * 4) = ea / (ea + eb);
        }
    }
    __syncthreads();

    // ---------- E1: H1 = relu(blend(S @ ew1[e]^T [+eb1 via pad]))  M=32 N=256x2 K=384 ----------
    #pragma unroll 1
    for (int p = 0; p < 2; ++p) {
        f32x4 aA[2], aB[2];
        #pragma unroll
        for (int mt = 0; mt < 2; ++mt) { aA[mt] = {0,0,0,0}; aB[mt] = {0,0,0,0}; }
        auto ldE1 = [&](int kc, int ex) -> half8 {
            if constexpr (USE_WS) {
                const int n0 = wv * 2 + p + ex * 16;
                return *(const half8*)(wsw + WS_E1 + (n0 * 12 + kc) * 512 + lB);
            } else {
                const int g = kc * 4 + kgrp;
                const int wr = wv * 32 + p * 16 + l15 + ex * 256;
                if (g < 47) return cvt8(ew1 + wr * 376 + g * 8);
                half8 rr = zf; rr[0] = (_Float16)eb1[wr]; return rr;
            }
        };
        half8 b0q[2] = { ldE1(0, 0), ldE1(1, 0) };
        half8 b1q[2] = { ldE1(0, 1), ldE1(1, 1) };
        #pragma unroll
        for (int kc = 0; kc < 12; ++kc) {
            const half8 c0f = b0q[kc & 1], c1f = b1q[kc & 1];
            if (kc + 2 < 12) { b0q[kc & 1] = ldE1(kc + 2, 0); b1q[kc & 1] = ldE1(kc + 2, 1); }
            const int koff = kc * 64 + kg16;
            #pragma unroll
            for (int mt = 0; mt < 2; ++mt) {
                const int row = mt * 16 + l15;
                const half8 af = *(const half8*)(smc + S_B + ((row * 768 + koff) ^ SWZ(row)));
                aA[mt] = MFMA16(af, c0f, aA[mt]);
                aB[mt] = MFMA16(af, c1f, aB[mt]);
            }
        }
        MFMA_FENCE();
        const int col = wv * 32 + p * 16 + l15;
        #pragma unroll
        for (int mt = 0; mt < 2; ++mt) {
            #pragma unroll
            for (int j = 0; j < 4; ++j) {
                const int row = mt * 16 + kgrp * 4 + j;
                const float2 cc = *(const float2*)(smc + CF_B + row * 8);
                const float v = fmaxf(cc.x * aA[mt][j] + cc.y * aB[mt][j], 0.f);  // bias in acc
                *(_Float16*)(smc + H1_B + ((row * 512 + col * 2) ^ SWZ(row))) = (_Float16)v;
            }
        }
    }
    __syncthreads();

    // ---------- E2: H2 = relu(blend(H1 @ ew2[e]^T + eb2[e]))  M=32 N=128x2 K=256 ----------
    {
        f32x4 cA[2], cB[2];
        #pragma unroll
        for (int mt = 0; mt < 2; ++mt) { cA[mt] = {0,0,0,0}; cB[mt] = {0,0,0,0}; }
        const int col = wv * 16 + l15;
        auto ldE2 = [&](int kc, int ex) -> half8 {
            if constexpr (USE_WS) {
                return *(const half8*)(wsw + WS_E2 + ((wv + ex * 8) * 8 + kc) * 512 + lB);
            } else {
                const int g = kc * 4 + kgrp;
                return cvt8(ew2 + (col + ex * 128) * 256 + g * 8);
            }
        };
        half8 b0q[2] = { ldE2(0, 0), ldE2(1, 0) };
        half8 b1q[2] = { ldE2(0, 1), ldE2(1, 1) };
        #pragma unroll
        for (int kc = 0; kc < 8; ++kc) {
            const half8 c0f = b0q[kc & 1], c1f = b1q[kc & 1];
            if (kc + 2 < 8) { b0q[kc & 1] = ldE2(kc + 2, 0); b1q[kc & 1] = ldE2(kc + 2, 1); }
            const int koff = kc * 64 + kg16;
            #pragma unroll
            for (int mt = 0; mt < 2; ++mt) {
                const int row = mt * 16 + l15;
                const half8 af = *(const half8*)(smc + H1_B + ((row * 512 + koff) ^ SWZ(row)));
                cA[mt] = MFMA16(af, c0f, cA[mt]);
                cB[mt] = MFMA16(af, c1f, cB[mt]);
            }
        }
        MFMA_FENCE();
        __syncthreads();   // all H1 reads done before H2 overlays H1 low half
        const float b0s = eb2[col], b1s = eb2[128 + col];
        #pragma unroll
        for (int mt = 0; mt < 2; ++mt) {
            #pragma unroll
            for (int j = 0; j < 4; ++j) {
                const int row = mt * 16 + kgrp * 4 + j;
                const float2 cc = *(const float2*)(smc + CF_B + row * 8);
                const float v = fmaxf(cc.x * (cA[mt][j] + b0s) + cc.y * (cB[mt][j] + b1s), 0.f);
                *(_Float16*)(smc + H2_B + ((row * 256 + col * 2) ^ SWZ(row))) = (_Float16)v;
            }
        }
    }
    __syncthreads();

    // ---------- E3: mu = tanh(blend(H2 @ ewm[e]^T + ebm[e]))  M=32 N=17x2 K=128 ----------
    if (wv < 4) {
        const int colt = wv & 1;
        const int mtq  = wv >> 1;
        f32x4 c0a = {0,0,0,0}, c1a = {0,0,0,0};
        const int col  = colt * 16 + l15;
        const bool vcol = (col < 17);
        const int arow = mtq * 16 + l15;
        for (int kc = 0; kc < 4; ++kc) {
            const int koff = kc * 64 + kg16;
            const half8 af = *(const half8*)(smc + H2_B + ((arow * 256 + koff) ^ SWZ(arow)));
            half8 b0, b1;
            if constexpr (USE_WS) {
                b0 = *(const half8*)(wsw + WS_EM + (colt * 4 + kc) * 512 + lB);
                b1 = *(const half8*)(wsw + WS_EM + ((2 + colt) * 4 + kc) * 512 + lB);
            } else {
                const int g = kc * 4 + kgrp;
                b0 = vcol ? cvt8(ewm + col * 128 + g * 8)        : zf;
                b1 = vcol ? cvt8(ewm + (17 + col) * 128 + g * 8) : zf;
            }
            c0a = MFMA16(af, b0, c0a);
            c1a = MFMA16(af, b1, c1a);
        }
        MFMA_FENCE();
        if (vcol) {
            const float b0 = ebm[col], b1 = ebm[17 + col];
            #pragma unroll
            for (int j = 0; j < 4; ++j) {
                const int row = mtq * 16 + kgrp * 4 + j;
                const float2 cc = *(const float2*)(smc + CF_B + row * 8);
                const float z = cc.x * (c0a[j] + b0) + cc.y * (c1a[j] + b1);
                const float e2x = __expf(2.f * z);
                out[(long)(base + row) * 17 + col] = 1.f - 2.f / (e2x + 1.f);
            }
        }
    }
}

extern "C" void kernel_launch(void* const* d_in, const int* in_sizes, int n_in,
                              void* d_out, int out_size, void* d_ws, size_t ws_size,
                              hipStream_t stream) {
    (void)in_sizes; (void)n_in; (void)out_size;
    const float* states = (const float*)d_in[0];
    const float* bw1 = (const float*)d_in[1];
    const float* bb1 = (const float*)d_in[2];
    const float* bw2 = (const float*)d_in[3];
    const float* bb2 = (const float*)d_in[4];
    const float* bwo = (const float*)d_in[5];
    const float* bbo = (const float*)d_in[6];
    const float* ew1 = (const float*)d_in[7];
    const float* eb1 = (const float*)d_in[8];
    const float* ew2 = (const float*)d_in[9];
    const float* eb2 = (const float*)d_in[10];
    const float* ewm = (const float*)d_in[11];
    const float* ebm = (const float*)d_in[12];
    float* out = (float*)d_out;

    const int nblk = 65536 / MT;   // 2048

    if (d_ws != nullptr && ws_size >= (size_t)WS_BYTES) {
        _Float16* wsw = (_Float16*)d_ws;
        prep_weights<<<dim3((WS_HALFS + 255) / 256), dim3(256), 0, stream>>>(
            bw1, bb1, bw2, ew1, eb1, ew2, ewm, wsw);
        actor_kernel<true><<<dim3(nblk), dim3(T), LDS_BYTES, stream>>>(
            states, bw1, bb1, bw2, bb2, bwo, bbo,
            ew1, eb1, ew2, eb2, ewm, ebm, wsw, out);
    } else {
        actor_kernel<false><<<dim3(nblk), dim3(T), LDS_BYTES, stream>>>(
            states, bw1, bb1, bw2, bb2, bwo, bbo,
            ew1, eb1, ew2, eb2, ewm, ebm, nullptr, out);
    }
}

// Round 22
// 108.926 us; speedup vs baseline: 1.1800x; 1.1800x over previous
//
#include <hip/hip_runtime.h>
#include <math.h>

// Fused Actor network via single-term fp16 MFMA. Round 22: r21 + waves_per_eu(3,3).
// Empirical allocator law from r8/r10/r12/r20/r21: chosen budget ~= 512/(2*request)
// ((2)->120, (4,4)->64, (6,6)->40) -- the attribute appears to be interpreted at 2x
// the intended wave64 count. To get the 6-wave/SIMD budget (~85 regs) request 3.
// Demand ~75 regs (asm-MFMA, "+v"-pinned accs, no AGPR granule) <= 80-85 -> no spill,
// occupancy 6 waves/SIMD = 3 blocks/CU (LDS 3x41216 <= 160K, schedulable per r20).
// Single change vs r21. Block = 32 samples, 512 threads = 8 waves, LDS 41,216 B.
// Bias-fold, f32 coeffs in CF, fast tanh, depth-2 prefetch, hazard-fenced asm MFMA.
// Weights pre-tiled in d_ws (per-wave 1KB bursts). LDS XOR-swizzle byte^=(row&7)<<4.

typedef __attribute__((ext_vector_type(8))) _Float16 half8;
typedef __attribute__((ext_vector_type(4))) _Float16 half4;
typedef __attribute__((ext_vector_type(4))) float    f32x4;

__device__ __forceinline__ f32x4 mfma16(half8 a, half8 b, f32x4 c) {
    // s_nop 1: 2 wait states for any VALU write (acc init / copies) -> MFMA read.
    // "v" = VGPR class -> no 64-AGPR allocation granule.
    asm("s_nop 1\n\tv_mfma_f32_16x16x32_f16 %0, %1, %2, %0" : "+v"(c) : "v"(a), "v"(b));
    return c;
}
#define MFMA16(a, b, c) mfma16((a), (b), (c))
// fence between MFMA chain and VALU reads of results (rule #18: sched_barrier pins
// ordering; s_nops cover MFMA-write -> VALU-read wait states).
#define MFMA_FENCE() do {                                    \
    __builtin_amdgcn_sched_barrier(0);                       \
    asm volatile("s_nop 7\n\ts_nop 7" ::: );                 \
    __builtin_amdgcn_sched_barrier(0);                       \
} while (0)

#define SWZ(row) (((row) & 7) << 4)

#define MT 32
#define T  512

// ---- LDS byte offsets (total 41,216 B) ----
// S  [0, 24576): 32 rows x 384 f16 (stride 768B); col376 = 1.0 (bias), 377..383 = 0.
// G1 [24576, 32768): 32x128 f16 (stride 256B)
// G2 [32768, 40960): 32x128 f16
// H1 [24576, 40960): 32x256 f16 (stride 512B), overlays G1+G2 (dead after A3)
// H2 [24576, 32768): 32x128 f16, overlays H1 low half (barrier inside E2)
// CF [40960, 41216): 32 x (c0,c1) f32
#define S_B      0
#define G1_B     24576
#define G2_B     32768
#define H1_B     24576
#define H2_B     24576
#define CF_B     40960
#define LDS_BYTES 41216

// ---- ws half-element offsets; tiled: tile(n0,kc) at ((n0*KC+kc)*512), [lane][8] ----
#define WS_W1 0        /* bw1: N0=8,  KC=12 (k=376 holds bb1) */
#define WS_W2 49152    /* bw2: N0=8,  KC=4 */
#define WS_E1 65536    /* ew1: N0=32, KC=12 (k=376 holds eb1) */
#define WS_E2 262144   /* ew2: N0=16, KC=8 */
#define WS_EM 327680   /* ewm: N0=4,  KC=4 (2 experts x 32 rows padded) */
#define WS_HALFS 335872
#define WS_BYTES 671744

__device__ __forceinline__ half8 cvt8(const float* __restrict__ p) {
    const float4 a = *reinterpret_cast<const float4*>(p);
    const float4 b = *reinterpret_cast<const float4*>(p + 4);
    half8 r;
    r[0] = (_Float16)a.x; r[1] = (_Float16)a.y; r[2] = (_Float16)a.z; r[3] = (_Float16)a.w;
    r[4] = (_Float16)b.x; r[5] = (_Float16)b.y; r[6] = (_Float16)b.z; r[7] = (_Float16)b.w;
    return r;
}

// ================= prep kernel: fp32 weights -> fp16 B-fragment tiles in ws =================
__global__ __launch_bounds__(256)
void prep_weights(const float* __restrict__ bw1, const float* __restrict__ bb1,
                  const float* __restrict__ bw2,
                  const float* __restrict__ ew1, const float* __restrict__ eb1,
                  const float* __restrict__ ew2,
                  const float* __restrict__ ewm, _Float16* __restrict__ wsw)
{
    const int i = blockIdx.x * 256 + threadIdx.x;
    if (i >= WS_HALFS) return;
    int sec; const float* W; const float* Bv; int N, K, KC, j0;
    if      (i < 49152)  { sec = 0; W = bw1; Bv = bb1;     N = 128; K = 376; KC = 12; j0 = i - WS_W1; }
    else if (i < 65536)  { sec = 1; W = bw2; Bv = nullptr; N = 128; K = 128; KC = 4;  j0 = i - WS_W2; }
    else if (i < 262144) { sec = 2; W = ew1; Bv = eb1;     N = 512; K = 376; KC = 12; j0 = i - WS_E1; }
    else if (i < 327680) { sec = 3; W = ew2; Bv = nullptr; N = 256; K = 256; KC = 8;  j0 = i - WS_E2; }
    else                 { sec = 4; W = ewm; Bv = nullptr; N = 34;  K = 128; KC = 4;  j0 = i - WS_EM; }
    const int tile = j0 >> 9;
    const int rem  = j0 & 511;
    const int l    = rem >> 3;
    const int jj   = rem & 7;
    const int n0   = tile / KC, kc = tile - n0 * KC;
    const int n = n0 * 16 + (l & 15);
    const int k = kc * 32 + (l >> 4) * 8 + jj;
    float v = 0.f;
    if (sec == 4) {
        const int e = n >> 5, a = n & 31;
        if (a < 17 && k < K) v = ewm[(e * 17 + a) * K + k];
    } else if (n < N) {
        if (k < K)             v = W[n * K + k];
        else if (k == K && Bv) v = Bv[n];
    }
    wsw[i] = (_Float16)v;
}

// ================= fused actor kernel =================
template <bool USE_WS>
__global__ __launch_bounds__(512)
__attribute__((amdgpu_waves_per_eu(3, 3)))
void actor_kernel(const float* __restrict__ states,
                  const float* __restrict__ bw1, const float* __restrict__ bb1,
                  const float* __restrict__ bw2, const float* __restrict__ bb2,
                  const float* __restrict__ bwo, const float* __restrict__ bbo,
                  const float* __restrict__ ew1, const float* __restrict__ eb1,
                  const float* __restrict__ ew2, const float* __restrict__ eb2,
                  const float* __restrict__ ewm, const float* __restrict__ ebm,
                  const _Float16* __restrict__ wsw,
                  float* __restrict__ out)
{
    extern __shared__ char smc[];
    const int t    = threadIdx.x;
    const int l    = t & 63;
    const int l15  = l & 15;
    const int kgrp = l >> 4;
    const int kg16 = kgrp * 16;
    const int wv   = __builtin_amdgcn_readfirstlane(t >> 6);
    const int base = blockIdx.x * MT;
    const int lB   = l * 8;

    const half8 zf = {0,0,0,0,0,0,0,0};

    // ---------- stage ----------
    {
        const float4* src = reinterpret_cast<const float4*>(states + (long)base * 376);
        for (int q = t; q < MT * 94; q += T) {
            const int r  = q / 94;
            const int c4 = q - r * 94;
            const float4 v = src[q];
            half4 h;
            h[0] = (_Float16)v.x; h[1] = (_Float16)v.y;
            h[2] = (_Float16)v.z; h[3] = (_Float16)v.w;
            *(half4*)(smc + S_B + ((r * 768 + c4 * 8) ^ SWZ(r))) = h;
        }
        if (t < MT) {
            const int off = (t * 768 + 752) ^ SWZ(t);
            *(ushort4*)(smc + S_B + off)     = make_ushort4(0x3C00u, 0, 0, 0);
            *(ushort4*)(smc + S_B + off + 8) = make_ushort4(0, 0, 0, 0);
        }
    }
    __syncthreads();

    // ---------- A1: G1 = relu(S @ bw1^T [+bb1 via pad])  M=32 N=128 K=384 ----------
    {
        f32x4 acc[2] = {{0,0,0,0},{0,0,0,0}};
        const int col = wv * 16 + l15;
        auto ldW = [&](int kc) -> half8 {
            if constexpr (USE_WS) return *(const half8*)(wsw + WS_W1 + (wv * 12 + kc) * 512 + lB);
            else {
                const int g = kc * 4 + kgrp;
                if (g < 47) return cvt8(bw1 + col * 376 + g * 8);
                half8 rr = zf; rr[0] = (_Float16)bb1[col]; return rr;
            }
        };
        half8 bq[2] = { ldW(0), ldW(1) };
        #pragma unroll
        for (int kc = 0; kc < 12; ++kc) {
            const half8 cur = bq[kc & 1];
            if (kc + 2 < 12) bq[kc & 1] = ldW(kc + 2);
            const int koff = kc * 64 + kg16;
            #pragma unroll
            for (int mt = 0; mt < 2; ++mt) {
                const int row = mt * 16 + l15;
                const half8 af = *(const half8*)(smc + S_B + ((row * 768 + koff) ^ SWZ(row)));
                acc[mt] = MFMA16(af, cur, acc[mt]);
            }
        }
        MFMA_FENCE();
        #pragma unroll
        for (int mt = 0; mt < 2; ++mt) {
            #pragma unroll
            for (int j = 0; j < 4; ++j) {
                const int row = mt * 16 + kgrp * 4 + j;
                const float v = fmaxf(acc[mt][j], 0.f);   // bias in acc
                *(_Float16*)(smc + G1_B + ((row * 256 + col * 2) ^ SWZ(row))) = (_Float16)v;
            }
        }
    }
    __syncthreads();

    // ---------- A2: G2 = relu(G1 @ bw2^T + bb2)  M=32 N=128 K=128 ----------
    {
        f32x4 acc[2] = {{0,0,0,0},{0,0,0,0}};
        const int col = wv * 16 + l15;
        auto ldW = [&](int kc) -> half8 {
            if constexpr (USE_WS) return *(const half8*)(wsw + WS_W2 + (wv * 4 + kc) * 512 + lB);
            else                  return cvt8(bw2 + col * 128 + (kc * 4 + kgrp) * 8);
        };
        half8 bq[2] = { ldW(0), ldW(1) };
        #pragma unroll
        for (int kc = 0; kc < 4; ++kc) {
            const half8 cur = bq[kc & 1];
            if (kc + 2 < 4) bq[kc & 1] = ldW(kc + 2);
            const int koff = kc * 64 + kg16;
            #pragma unroll
            for (int mt = 0; mt < 2; ++mt) {
                const int row = mt * 16 + l15;
                const half8 af = *(const half8*)(smc + G1_B + ((row * 256 + koff) ^ SWZ(row)));
                acc[mt] = MFMA16(af, cur, acc[mt]);
            }
        }
        MFMA_FENCE();
        const float bias = bb2[col];
        #pragma unroll
        for (int mt = 0; mt < 2; ++mt) {
            #pragma unroll
            for (int j = 0; j < 4; ++j) {
                const int row = mt * 16 + kgrp * 4 + j;
                const float v = fmaxf(acc[mt][j] + bias, 0.f);
                *(_Float16*)(smc + G2_B + ((row * 256 + col * 2) ^ SWZ(row))) = (_Float16)v;
            }
        }
    }
    __syncthreads();

    // ---------- A3: softmax coeffs -> f32 (c0,c1) in CF ----------
    {
        const int s     = t >> 4;
        const int r     = t & 15;
        const int e     = r & 1;
        const int chunk = r >> 1;
        float z = 0.f;
        const float* wo = bwo + e * 128 + chunk * 16;
        #pragma unroll
        for (int q = 0; q < 2; ++q) {
            const half8 hv = *(const half8*)(smc + G2_B + ((s * 256 + chunk * 32 + q * 16) ^ SWZ(s)));
            const float4 w0 = *(const float4*)(wo + q * 8);
            const float4 w1 = *(const float4*)(wo + q * 8 + 4);
            z = fmaf((float)hv[0], w0.x, z); z = fmaf((float)hv[1], w0.y, z);
            z = fmaf((float)hv[2], w0.z, z); z = fmaf((float)hv[3], w0.w, z);
            z = fmaf((float)hv[4], w1.x, z); z = fmaf((float)hv[5], w1.y, z);
            z = fmaf((float)hv[6], w1.z, z); z = fmaf((float)hv[7], w1.w, z);
        }
        z += __shfl_xor(z, 2, 64);
        z += __shfl_xor(z, 4, 64);
        z += __shfl_xor(z, 8, 64);
        z += bbo[e];
        const float zo = __shfl_xor(z, 1, 64);
        if (r < 2) {
            const float m = fmaxf(z, zo);
            const float ea = __expf(z - m), eb = __expf(zo - m);
            *(float*)(smc + CF_B + s * 8 + e * 4) = ea / (ea + eb);
        }
    }
    __syncthreads();

    // ---------- E1: H1 = relu(blend(S @ ew1[e]^T [+eb1 via pad]))  M=32 N=256x2 K=384 ----------
    #pragma unroll 1
    for (int p = 0; p < 2; ++p) {
        f32x4 aA[2], aB[2];
        #pragma unroll
        for (int mt = 0; mt < 2; ++mt) { aA[mt] = {0,0,0,0}; aB[mt] = {0,0,0,0}; }
        auto ldE1 = [&](int kc, int ex) -> half8 {
            if constexpr (USE_WS) {
                const int n0 = wv * 2 + p + ex * 16;
                return *(const half8*)(wsw + WS_E1 + (n0 * 12 + kc) * 512 + lB);
            } else {
                const int g = kc * 4 + kgrp;
                const int wr = wv * 32 + p * 16 + l15 + ex * 256;
                if (g < 47) return cvt8(ew1 + wr * 376 + g * 8);
                half8 rr = zf; rr[0] = (_Float16)eb1[wr]; return rr;
            }
        };
        half8 b0q[2] = { ldE1(0, 0), ldE1(1, 0) };
        half8 b1q[2] = { ldE1(0, 1), ldE1(1, 1) };
        #pragma unroll
        for (int kc = 0; kc < 12; ++kc) {
            const half8 c0f = b0q[kc & 1], c1f = b1q[kc & 1];
            if (kc + 2 < 12) { b0q[kc & 1] = ldE1(kc + 2, 0); b1q[kc & 1] = ldE1(kc + 2, 1); }
            const int koff = kc * 64 + kg16;
            #pragma unroll
            for (int mt = 0; mt < 2; ++mt) {
                const int row = mt * 16 + l15;
                const half8 af = *(const half8*)(smc + S_B + ((row * 768 + koff) ^ SWZ(row)));
                aA[mt] = MFMA16(af, c0f, aA[mt]);
                aB[mt] = MFMA16(af, c1f, aB[mt]);
            }
        }
        MFMA_FENCE();
        const int col = wv * 32 + p * 16 + l15;
        #pragma unroll
        for (int mt = 0; mt < 2; ++mt) {
            #pragma unroll
            for (int j = 0; j < 4; ++j) {
                const int row = mt * 16 + kgrp * 4 + j;
                const float2 cc = *(const float2*)(smc + CF_B + row * 8);
                const float v = fmaxf(cc.x * aA[mt][j] + cc.y * aB[mt][j], 0.f);  // bias in acc
                *(_Float16*)(smc + H1_B + ((row * 512 + col * 2) ^ SWZ(row))) = (_Float16)v;
            }
        }
    }
    __syncthreads();

    // ---------- E2: H2 = relu(blend(H1 @ ew2[e]^T + eb2[e]))  M=32 N=128x2 K=256 ----------
    {
        f32x4 cA[2], cB[2];
        #pragma unroll
        for (int mt = 0; mt < 2; ++mt) { cA[mt] = {0,0,0,0}; cB[mt] = {0,0,0,0}; }
        const int col = wv * 16 + l15;
        auto ldE2 = [&](int kc, int ex) -> half8 {
            if constexpr (USE_WS) {
                return *(const half8*)(wsw + WS_E2 + ((wv + ex * 8) * 8 + kc) * 512 + lB);
            } else {
                const int g = kc * 4 + kgrp;
                return cvt8(ew2 + (col + ex * 128) * 256 + g * 8);
            }
        };
        half8 b0q[2] = { ldE2(0, 0), ldE2(1, 0) };
        half8 b1q[2] = { ldE2(0, 1), ldE2(1, 1) };
        #pragma unroll
        for (int kc = 0; kc < 8; ++kc) {
            const half8 c0f = b0q[kc & 1], c1f = b1q[kc & 1];
            if (kc + 2 < 8) { b0q[kc & 1] = ldE2(kc + 2, 0); b1q[kc & 1] = ldE2(kc + 2, 1); }
            const int koff = kc * 64 + kg16;
            #pragma unroll
            for (int mt = 0; mt < 2; ++mt) {
                const int row = mt * 16 + l15;
                const half8 af = *(const half8*)(smc + H1_B + ((row * 512 + koff) ^ SWZ(row)));
                cA[mt] = MFMA16(af, c0f, cA[mt]);
                cB[mt] = MFMA16(af, c1f, cB[mt]);
            }
        }
        MFMA_FENCE();
        __syncthreads();   // all H1 reads done before H2 overlays H1 low half
        const float b0s = eb2[col], b1s = eb2[128 + col];
        #pragma unroll
        for (int mt = 0; mt < 2; ++mt) {
            #pragma unroll
            for (int j = 0; j < 4; ++j) {
                const int row = mt * 16 + kgrp * 4 + j;
                const float2 cc = *(const float2*)(smc + CF_B + row * 8);
                const float v = fmaxf(cc.x * (cA[mt][j] + b0s) + cc.y * (cB[mt][j] + b1s), 0.f);
                *(_Float16*)(smc + H2_B + ((row * 256 + col * 2) ^ SWZ(row))) = (_Float16)v;
            }
        }
    }
    __syncthreads();

    // ---------- E3: mu = tanh(blend(H2 @ ewm[e]^T + ebm[e]))  M=32 N=17x2 K=128 ----------
    if (wv < 4) {
        const int colt = wv & 1;
        const int mtq  = wv >> 1;
        f32x4 c0a = {0,0,0,0}, c1a = {0,0,0,0};
        const int col  = colt * 16 + l15;
        const bool vcol = (col < 17);
        const int arow = mtq * 16 + l15;
        for (int kc = 0; kc < 4; ++kc) {
            const int koff = kc * 64 + kg16;
            const half8 af = *(const half8*)(smc + H2_B + ((arow * 256 + koff) ^ SWZ(arow)));
            half8 b0, b1;
            if constexpr (USE_WS) {
                b0 = *(const half8*)(wsw + WS_EM + (colt * 4 + kc) * 512 + lB);
                b1 = *(const half8*)(wsw + WS_EM + ((2 + colt) * 4 + kc) * 512 + lB);
            } else {
                const int g = kc * 4 + kgrp;
                b0 = vcol ? cvt8(ewm + col * 128 + g * 8)        : zf;
                b1 = vcol ? cvt8(ewm + (17 + col) * 128 + g * 8) : zf;
            }
            c0a = MFMA16(af, b0, c0a);
            c1a = MFMA16(af, b1, c1a);
        }
        MFMA_FENCE();
        if (vcol) {
            const float b0 = ebm[col], b1 = ebm[17 + col];
            #pragma unroll
            for (int j = 0; j < 4; ++j) {
                const int row = mtq * 16 + kgrp * 4 + j;
                const float2 cc = *(const float2*)(smc + CF_B + row * 8);
                const float z = cc.x * (c0a[j] + b0) + cc.y * (c1a[j] + b1);
                const float e2x = __expf(2.f * z);
                out[(long)(base + row) * 17 + col] = 1.f - 2.f / (e2x + 1.f);
            }
        }
    }
}

extern "C" void kernel_launch(void* const* d_in, const int* in_sizes, int n_in,
                              void* d_out, int out_size, void* d_ws, size_t ws_size,
                              hipStream_t stream) {
    (void)in_sizes; (void)n_in; (void)out_size;
    const float* states = (const float*)d_in[0];
    const float* bw1 = (const float*)d_in[1];
    const float* bb1 = (const float*)d_in[2];
    const float* bw2 = (const float*)d_in[3];
    const float* bb2 = (const float*)d_in[4];
    const float* bwo = (const float*)d_in[5];
    const float* bbo = (const float*)d_in[6];
    const float* ew1 = (const float*)d_in[7];
    const float* eb1 = (const float*)d_in[8];
    const float* ew2 = (const float*)d_in[9];
    const float* eb2 = (const float*)d_in[10];
    const float* ewm = (const float*)d_in[11];
    const float* ebm = (const float*)d_in[12];
    float* out = (float*)d_out;

    const int nblk = 65536 / MT;   // 2048

    if (d_ws != nullptr && ws_size >= (size_t)WS_BYTES) {
        _Float16* wsw = (_Float16*)d_ws;
        prep_weights<<<dim3((WS_HALFS + 255) / 256), dim3(256), 0, stream>>>(
            bw1, bb1, bw2, ew1, eb1, ew2, ewm, wsw);
        actor_kernel<true><<<dim3(nblk), dim3(T), LDS_BYTES, stream>>>(
            states, bw1, bb1, bw2, bb2, bwo, bbo,
            ew1, eb1, ew2, eb2, ewm, ebm, wsw, out);
    } else {
        actor_kernel<false><<<dim3(nblk), dim3(T), LDS_BYTES, stream>>>(
            states, bw1, bb1, bw2, bb2, bwo, bbo,
            ew1, eb1, ew2, eb2, ewm, ebm, nullptr, out);
    }
}

// Round 23
// 91.029 us; speedup vs baseline: 1.4120x; 1.1966x over previous
//
#include <hip/hip_runtime.h>
#include <math.h>

// Fused Actor network via single-term fp16 MFMA. Round 23: r22 + waves_per_eu(2).
// Completed allocator model (r8/r10/r12/r20/r21/r22):
//   - MIN bound sets the allocator squeeze target: min=4 -> 64 regs, min=6 -> 40 (spills);
//     min=2/3 -> relaxed to ~demand (no spill).
//   - MAX bound is written to the kernel descriptor and HARDWARE-caps waves/EU
//     (r22: (3,3) -> 68 regs, no spill, but occupancy capped at 1 block/CU).
// r22 measured true demand of this asm-MFMA kernel: 68 regs, zero spill.
// With (2): relaxed budget, no cap -> occupancy follows usage: floor(512/68)=7 waves/SIMD
// reg-wise, LDS caps at 3 blocks/CU = 6 waves/SIMD = 24 waves/CU (vs r18's 16).
// Single change vs r22. Block = 32 samples, 512 threads = 8 waves, LDS 41,216 B.
// Bias-fold, f32 coeffs in CF, fast tanh, depth-2 prefetch, hazard-fenced asm MFMA.
// Weights pre-tiled in d_ws (per-wave 1KB bursts). LDS XOR-swizzle byte^=(row&7)<<4.

typedef __attribute__((ext_vector_type(8))) _Float16 half8;
typedef __attribute__((ext_vector_type(4))) _Float16 half4;
typedef __attribute__((ext_vector_type(4))) float    f32x4;

__device__ __forceinline__ f32x4 mfma16(half8 a, half8 b, f32x4 c) {
    // s_nop 1: 2 wait states for any VALU write (acc init / copies) -> MFMA read.
    // "v" = VGPR class -> no 64-AGPR allocation granule.
    asm("s_nop 1\n\tv_mfma_f32_16x16x32_f16 %0, %1, %2, %0" : "+v"(c) : "v"(a), "v"(b));
    return c;
}
#define MFMA16(a, b, c) mfma16((a), (b), (c))
// fence between MFMA chain and VALU reads of results (rule #18: sched_barrier pins
// ordering; s_nops cover MFMA-write -> VALU-read wait states).
#define MFMA_FENCE() do {                                    \
    __builtin_amdgcn_sched_barrier(0);                       \
    asm volatile("s_nop 7\n\ts_nop 7" ::: );                 \
    __builtin_amdgcn_sched_barrier(0);                       \
} while (0)

#define SWZ(row) (((row) & 7) << 4)

#define MT 32
#define T  512

// ---- LDS byte offsets (total 41,216 B) ----
// S  [0, 24576): 32 rows x 384 f16 (stride 768B); col376 = 1.0 (bias), 377..383 = 0.
// G1 [24576, 32768): 32x128 f16 (stride 256B)
// G2 [32768, 40960): 32x128 f16
// H1 [24576, 40960): 32x256 f16 (stride 512B), overlays G1+G2 (dead after A3)
// H2 [24576, 32768): 32x128 f16, overlays H1 low half (barrier inside E2)
// CF [40960, 41216): 32 x (c0,c1) f32
#define S_B      0
#define G1_B     24576
#define G2_B     32768
#define H1_B     24576
#define H2_B     24576
#define CF_B     40960
#define LDS_BYTES 41216

// ---- ws half-element offsets; tiled: tile(n0,kc) at ((n0*KC+kc)*512), [lane][8] ----
#define WS_W1 0        /* bw1: N0=8,  KC=12 (k=376 holds bb1) */
#define WS_W2 49152    /* bw2: N0=8,  KC=4 */
#define WS_E1 65536    /* ew1: N0=32, KC=12 (k=376 holds eb1) */
#define WS_E2 262144   /* ew2: N0=16, KC=8 */
#define WS_EM 327680   /* ewm: N0=4,  KC=4 (2 experts x 32 rows padded) */
#define WS_HALFS 335872
#define WS_BYTES 671744

__device__ __forceinline__ half8 cvt8(const float* __restrict__ p) {
    const float4 a = *reinterpret_cast<const float4*>(p);
    const float4 b = *reinterpret_cast<const float4*>(p + 4);
    half8 r;
    r[0] = (_Float16)a.x; r[1] = (_Float16)a.y; r[2] = (_Float16)a.z; r[3] = (_Float16)a.w;
    r[4] = (_Float16)b.x; r[5] = (_Float16)b.y; r[6] = (_Float16)b.z; r[7] = (_Float16)b.w;
    return r;
}

// ================= prep kernel: fp32 weights -> fp16 B-fragment tiles in ws =================
__global__ __launch_bounds__(256)
void prep_weights(const float* __restrict__ bw1, const float* __restrict__ bb1,
                  const float* __restrict__ bw2,
                  const float* __restrict__ ew1, const float* __restrict__ eb1,
                  const float* __restrict__ ew2,
                  const float* __restrict__ ewm, _Float16* __restrict__ wsw)
{
    const int i = blockIdx.x * 256 + threadIdx.x;
    if (i >= WS_HALFS) return;
    int sec; const float* W; const float* Bv; int N, K, KC, j0;
    if      (i < 49152)  { sec = 0; W = bw1; Bv = bb1;     N = 128; K = 376; KC = 12; j0 = i - WS_W1; }
    else if (i < 65536)  { sec = 1; W = bw2; Bv = nullptr; N = 128; K = 128; KC = 4;  j0 = i - WS_W2; }
    else if (i < 262144) { sec = 2; W = ew1; Bv = eb1;     N = 512; K = 376; KC = 12; j0 = i - WS_E1; }
    else if (i < 327680) { sec = 3; W = ew2; Bv = nullptr; N = 256; K = 256; KC = 8;  j0 = i - WS_E2; }
    else                 { sec = 4; W = ewm; Bv = nullptr; N = 34;  K = 128; KC = 4;  j0 = i - WS_EM; }
    const int tile = j0 >> 9;
    const int rem  = j0 & 511;
    const int l    = rem >> 3;
    const int jj   = rem & 7;
    const int n0   = tile / KC, kc = tile - n0 * KC;
    const int n = n0 * 16 + (l & 15);
    const int k = kc * 32 + (l >> 4) * 8 + jj;
    float v = 0.f;
    if (sec == 4) {
        const int e = n >> 5, a = n & 31;
        if (a < 17 && k < K) v = ewm[(e * 17 + a) * K + k];
    } else if (n < N) {
        if (k < K)             v = W[n * K + k];
        else if (k == K && Bv) v = Bv[n];
    }
    wsw[i] = (_Float16)v;
}

// ================= fused actor kernel =================
template <bool USE_WS>
__global__ __launch_bounds__(512)
__attribute__((amdgpu_waves_per_eu(2)))
void actor_kernel(const float* __restrict__ states,
                  const float* __restrict__ bw1, const float* __restrict__ bb1,
                  const float* __restrict__ bw2, const float* __restrict__ bb2,
                  const float* __restrict__ bwo, const float* __restrict__ bbo,
                  const float* __restrict__ ew1, const float* __restrict__ eb1,
                  const float* __restrict__ ew2, const float* __restrict__ eb2,
                  const float* __restrict__ ewm, const float* __restrict__ ebm,
                  const _Float16* __restrict__ wsw,
                  float* __restrict__ out)
{
    extern __shared__ char smc[];
    const int t    = threadIdx.x;
    const int l    = t & 63;
    const int l15  = l & 15;
    const int kgrp = l >> 4;
    const int kg16 = kgrp * 16;
    const int wv   = __builtin_amdgcn_readfirstlane(t >> 6);
    const int base = blockIdx.x * MT;
    const int lB   = l * 8;

    const half8 zf = {0,0,0,0,0,0,0,0};

    // ---------- stage ----------
    {
        const float4* src = reinterpret_cast<const float4*>(states + (long)base * 376);
        for (int q = t; q < MT * 94; q += T) {
            const int r  = q / 94;
            const int c4 = q - r * 94;
            const float4 v = src[q];
            half4 h;
            h[0] = (_Float16)v.x; h[1] = (_Float16)v.y;
            h[2] = (_Float16)v.z; h[3] = (_Float16)v.w;
            *(half4*)(smc + S_B + ((r * 768 + c4 * 8) ^ SWZ(r))) = h;
        }
        if (t < MT) {
            const int off = (t * 768 + 752) ^ SWZ(t);
            *(ushort4*)(smc + S_B + off)     = make_ushort4(0x3C00u, 0, 0, 0);
            *(ushort4*)(smc + S_B + off + 8) = make_ushort4(0, 0, 0, 0);
        }
    }
    __syncthreads();

    // ---------- A1: G1 = relu(S @ bw1^T [+bb1 via pad])  M=32 N=128 K=384 ----------
    {
        f32x4 acc[2] = {{0,0,0,0},{0,0,0,0}};
        const int col = wv * 16 + l15;
        auto ldW = [&](int kc) -> half8 {
            if constexpr (USE_WS) return *(const half8*)(wsw + WS_W1 + (wv * 12 + kc) * 512 + lB);
            else {
                const int g = kc * 4 + kgrp;
                if (g < 47) return cvt8(bw1 + col * 376 + g * 8);
                half8 rr = zf; rr[0] = (_Float16)bb1[col]; return rr;
            }
        };
        half8 bq[2] = { ldW(0), ldW(1) };
        #pragma unroll
        for (int kc = 0; kc < 12; ++kc) {
            const half8 cur = bq[kc & 1];
            if (kc + 2 < 12) bq[kc & 1] = ldW(kc + 2);
            const int koff = kc * 64 + kg16;
            #pragma unroll
            for (int mt = 0; mt < 2; ++mt) {
                const int row = mt * 16 + l15;
                const half8 af = *(const half8*)(smc + S_B + ((row * 768 + koff) ^ SWZ(row)));
                acc[mt] = MFMA16(af, cur, acc[mt]);
            }
        }
        MFMA_FENCE();
        #pragma unroll
        for (int mt = 0; mt < 2; ++mt) {
            #pragma unroll
            for (int j = 0; j < 4; ++j) {
                const int row = mt * 16 + kgrp * 4 + j;
                const float v = fmaxf(acc[mt][j], 0.f);   // bias in acc
                *(_Float16*)(smc + G1_B + ((row * 256 + col * 2) ^ SWZ(row))) = (_Float16)v;
            }
        }
    }
    __syncthreads();

    // ---------- A2: G2 = relu(G1 @ bw2^T + bb2)  M=32 N=128 K=128 ----------
    {
        f32x4 acc[2] = {{0,0,0,0},{0,0,0,0}};
        const int col = wv * 16 + l15;
        auto ldW = [&](int kc) -> half8 {
            if constexpr (USE_WS) return *(const half8*)(wsw + WS_W2 + (wv * 4 + kc) * 512 + lB);
            else                  return cvt8(bw2 + col * 128 + (kc * 4 + kgrp) * 8);
        };
        half8 bq[2] = { ldW(0), ldW(1) };
        #pragma unroll
        for (int kc = 0; kc < 4; ++kc) {
            const half8 cur = bq[kc & 1];
            if (kc + 2 < 4) bq[kc & 1] = ldW(kc + 2);
            const int koff = kc * 64 + kg16;
            #pragma unroll
            for (int mt = 0; mt < 2; ++mt) {
                const int row = mt * 16 + l15;
                const half8 af = *(const half8*)(smc + G1_B + ((row * 256 + koff) ^ SWZ(row)));
                acc[mt] = MFMA16(af, cur, acc[mt]);
            }
        }
        MFMA_FENCE();
        const float bias = bb2[col];
        #pragma unroll
        for (int mt = 0; mt < 2; ++mt) {
            #pragma unroll
            for (int j = 0; j < 4; ++j) {
                const int row = mt * 16 + kgrp * 4 + j;
                const float v = fmaxf(acc[mt][j] + bias, 0.f);
                *(_Float16*)(smc + G2_B + ((row * 256 + col * 2) ^ SWZ(row))) = (_Float16)v;
            }
        }
    }
    __syncthreads();

    // ---------- A3: softmax coeffs -> f32 (c0,c1) in CF ----------
    {
        const int s     = t >> 4;
        const int r     = t & 15;
        const int e     = r & 1;
        const int chunk = r >> 1;
        float z = 0.f;
        const float* wo = bwo + e * 128 + chunk * 16;
        #pragma unroll
        for (int q = 0; q < 2; ++q) {
            const half8 hv = *(const half8*)(smc + G2_B + ((s * 256 + chunk * 32 + q * 16) ^ SWZ(s)));
            const float4 w0 = *(const float4*)(wo + q * 8);
            const float4 w1 = *(const float4*)(wo + q * 8 + 4);
            z = fmaf((float)hv[0], w0.x, z); z = fmaf((float)hv[1], w0.y, z);
            z = fmaf((float)hv[2], w0.z, z); z = fmaf((float)hv[3], w0.w, z);
            z = fmaf((float)hv[4], w1.x, z); z = fmaf((float)hv[5], w1.y, z);
            z = fmaf((float)hv[6], w1.z, z); z = fmaf((float)hv[7], w1.w, z);
        }
        z += __shfl_xor(z, 2, 64);
        z += __shfl_xor(z, 4, 64);
        z += __shfl_xor(z, 8, 64);
        z += bbo[e];
        const float zo = __shfl_xor(z, 1, 64);
        if (r < 2) {
            const float m = fmaxf(z, zo);
            const float ea = __expf(z - m), eb = __expf(zo - m);
            *(float*)(smc + CF_B + s * 8 + e * 4) = ea / (ea + eb);
        }
    }
    __syncthreads();

    // ---------- E1: H1 = relu(blend(S @ ew1[e]^T [+eb1 via pad]))  M=32 N=256x2 K=384 ----------
    #pragma unroll 1
    for (int p = 0; p < 2; ++p) {
        f32x4 aA[2], aB[2];
        #pragma unroll
        for (int mt = 0; mt < 2; ++mt) { aA[mt] = {0,0,0,0}; aB[mt] = {0,0,0,0}; }
        auto ldE1 = [&](int kc, int ex) -> half8 {
            if constexpr (USE_WS) {
                const int n0 = wv * 2 + p + ex * 16;
                return *(const half8*)(wsw + WS_E1 + (n0 * 12 + kc) * 512 + lB);
            } else {
                const int g = kc * 4 + kgrp;
                const int wr = wv * 32 + p * 16 + l15 + ex * 256;
                if (g < 47) return cvt8(ew1 + wr * 376 + g * 8);
                half8 rr = zf; rr[0] = (_Float16)eb1[wr]; return rr;
            }
        };
        half8 b0q[2] = { ldE1(0, 0), ldE1(1, 0) };
        half8 b1q[2] = { ldE1(0, 1), ldE1(1, 1) };
        #pragma unroll
        for (int kc = 0; kc < 12; ++kc) {
            const half8 c0f = b0q[kc & 1], c1f = b1q[kc & 1];
            if (kc + 2 < 12) { b0q[kc & 1] = ldE1(kc + 2, 0); b1q[kc & 1] = ldE1(kc + 2, 1); }
            const int koff = kc * 64 + kg16;
            #pragma unroll
            for (int mt = 0; mt < 2; ++mt) {
                const int row = mt * 16 + l15;
                const half8 af = *(const half8*)(smc + S_B + ((row * 768 + koff) ^ SWZ(row)));
                aA[mt] = MFMA16(af, c0f, aA[mt]);
                aB[mt] = MFMA16(af, c1f, aB[mt]);
            }
        }
        MFMA_FENCE();
        const int col = wv * 32 + p * 16 + l15;
        #pragma unroll
        for (int mt = 0; mt < 2; ++mt) {
            #pragma unroll
            for (int j = 0; j < 4; ++j) {
                const int row = mt * 16 + kgrp * 4 + j;
                const float2 cc = *(const float2*)(smc + CF_B + row * 8);
                const float v = fmaxf(cc.x * aA[mt][j] + cc.y * aB[mt][j], 0.f);  // bias in acc
                *(_Float16*)(smc + H1_B + ((row * 512 + col * 2) ^ SWZ(row))) = (_Float16)v;
            }
        }
    }
    __syncthreads();

    // ---------- E2: H2 = relu(blend(H1 @ ew2[e]^T + eb2[e]))  M=32 N=128x2 K=256 ----------
    {
        f32x4 cA[2], cB[2];
        #pragma unroll
        for (int mt = 0; mt < 2; ++mt) { cA[mt] = {0,0,0,0}; cB[mt] = {0,0,0,0}; }
        const int col = wv * 16 + l15;
        auto ldE2 = [&](int kc, int ex) -> half8 {
            if constexpr (USE_WS) {
                return *(const half8*)(wsw + WS_E2 + ((wv + ex * 8) * 8 + kc) * 512 + lB);
            } else {
                const int g = kc * 4 + kgrp;
                return cvt8(ew2 + (col + ex * 128) * 256 + g * 8);
            }
        };
        half8 b0q[2] = { ldE2(0, 0), ldE2(1, 0) };
        half8 b1q[2] = { ldE2(0, 1), ldE2(1, 1) };
        #pragma unroll
        for (int kc = 0; kc < 8; ++kc) {
            const half8 c0f = b0q[kc & 1], c1f = b1q[kc & 1];
            if (kc + 2 < 8) { b0q[kc & 1] = ldE2(kc + 2, 0); b1q[kc & 1] = ldE2(kc + 2, 1); }
            const int koff = kc * 64 + kg16;
            #pragma unroll
            for (int mt = 0; mt < 2; ++mt) {
                const int row = mt * 16 + l15;
                const half8 af = *(const half8*)(smc + H1_B + ((row * 512 + koff) ^ SWZ(row)));
                cA[mt] = MFMA16(af, c0f, cA[mt]);
                cB[mt] = MFMA16(af, c1f, cB[mt]);
            }
        }
        MFMA_FENCE();
        __syncthreads();   // all H1 reads done before H2 overlays H1 low half
        const float b0s = eb2[col], b1s = eb2[128 + col];
        #pragma unroll
        for (int mt = 0; mt < 2; ++mt) {
            #pragma unroll
            for (int j = 0; j < 4; ++j) {
                const int row = mt * 16 + kgrp * 4 + j;
                const float2 cc = *(const float2*)(smc + CF_B + row * 8);
                const float v = fmaxf(cc.x * (cA[mt][j] + b0s) + cc.y * (cB[mt][j] + b1s), 0.f);
                *(_Float16*)(smc + H2_B + ((row * 256 + col * 2) ^ SWZ(row))) = (_Float16)v;
            }
        }
    }
    __syncthreads();

    // ---------- E3: mu = tanh(blend(H2 @ ewm[e]^T + ebm[e]))  M=32 N=17x2 K=128 ----------
    if (wv < 4) {
        const int colt = wv & 1;
        const int mtq  = wv >> 1;
        f32x4 c0a = {0,0,0,0}, c1a = {0,0,0,0};
        const int col  = colt * 16 + l15;
        const bool vcol = (col < 17);
        const int arow = mtq * 16 + l15;
        for (int kc = 0; kc < 4; ++kc) {
            const int koff = kc * 64 + kg16;
            const half8 af = *(const half8*)(smc + H2_B + ((arow * 256 + koff) ^ SWZ(arow)));
            half8 b0, b1;
            if constexpr (USE_WS) {
                b0 = *(const half8*)(wsw + WS_EM + (colt * 4 + kc) * 512 + lB);
                b1 = *(const half8*)(wsw + WS_EM + ((2 + colt) * 4 + kc) * 512 + lB);
            } else {
                const int g = kc * 4 + kgrp;
                b0 = vcol ? cvt8(ewm + col * 128 + g * 8)        : zf;
                b1 = vcol ? cvt8(ewm + (17 + col) * 128 + g * 8) : zf;
            }
            c0a = MFMA16(af, b0, c0a);
            c1a = MFMA16(af, b1, c1a);
        }
        MFMA_FENCE();
        if (vcol) {
            const float b0 = ebm[col], b1 = ebm[17 + col];
            #pragma unroll
            for (int j = 0; j < 4; ++j) {
                const int row = mtq * 16 + kgrp * 4 + j;
                const float2 cc = *(const float2*)(smc + CF_B + row * 8);
                const float z = cc.x * (c0a[j] + b0) + cc.y * (c1a[j] + b1);
                const float e2x = __expf(2.f * z);
                out[(long)(base + row) * 17 + col] = 1.f - 2.f / (e2x + 1.f);
            }
        }
    }
}

extern "C" void kernel_launch(void* const* d_in, const int* in_sizes, int n_in,
                              void* d_out, int out_size, void* d_ws, size_t ws_size,
                              hipStream_t stream) {
    (void)in_sizes; (void)n_in; (void)out_size;
    const float* states = (const float*)d_in[0];
    const float* bw1 = (const float*)d_in[1];
    const float* bb1 = (const float*)d_in[2];
    const float* bw2 = (const float*)d_in[3];
    const float* bb2 = (const float*)d_in[4];
    const float* bwo = (const float*)d_in[5];
    const float* bbo = (const float*)d_in[6];
    const float* ew1 = (const float*)d_in[7];
    const float* eb1 = (const float*)d_in[8];
    const float* ew2 = (const float*)d_in[9];
    const float* eb2 = (const float*)d_in[10];
    const float* ewm = (const float*)d_in[11];
    const float* ebm = (const float*)d_in[12];
    float* out = (float*)d_out;

    const int nblk = 65536 / MT;   // 2048

    if (d_ws != nullptr && ws_size >= (size_t)WS_BYTES) {
        _Float16* wsw = (_Float16*)d_ws;
        prep_weights<<<dim3((WS_HALFS + 255) / 256), dim3(256), 0, stream>>>(
            bw1, bb1, bw2, ew1, eb1, ew2, ewm, wsw);
        actor_kernel<true><<<dim3(nblk), dim3(T), LDS_BYTES, stream>>>(
            states, bw1, bb1, bw2, bb2, bwo, bbo,
            ew1, eb1, ew2, eb2, ewm, ebm, wsw, out);
    } else {
        actor_kernel<false><<<dim3(nblk), dim3(T), LDS_BYTES, stream>>>(
            states, bw1, bb1, bw2, bb2, bwo, bbo,
            ew1, eb1, ew2, eb2, ewm, ebm, nullptr, out);
    }
}